// Round 10
// baseline (1261.971 us; speedup 1.0000x reference)
//
#include <hip/hip_runtime.h>
#include <stdint.h>

// B=1024, N=16, D=64, H=64, A=64 -> 16384 nodes. All tensors fp32.
#define NNODE 16384
#define TAU_ 0.01f
#define EPSG 1e-10f

// ---- workspace layout (float offsets); total 1,114,112 floats = 4.25 MB ----
#define OFF_WENC 0
#define OFF_BENC 4096
#define OFF_WIHF 4160
#define OFF_WHHF 28736
#define OFF_BIHF 41024
#define OFF_BHHF 41216
#define OFF_WIHB 41408
#define OFF_WHHB 65984
#define OFF_BIHB 78272
#define OFF_BHHB 78464
#define OFF_WHARD 78656
#define OFF_BHARD 78912
#define OFF_WQ 78914
#define OFF_WK 83010
#define OFF_WV 87106
#define OFF_BV 91202
#define OFF_WIHC 91266
#define OFF_WHHC 103554
#define OFF_BIHC 115842
#define OFF_BHHC 116034
#define OFF_YF 131072
#define OFF_YB (OFF_YF + 491520)
#define WS_FLOATS (OFF_YB + 491520)

__device__ __forceinline__ float sigf(float x){ return 1.0f/(1.0f + __expf(-x)); }
__device__ __forceinline__ float tanhfast(float x){ return 1.0f - 2.0f/(__expf(2.0f*x)+1.0f); }

// ---------------- K0: copy all weights into contiguous ws ----------------
struct Prep {
  const float* s[20];
  int n[20];
  int o[20];
};
__global__ void k_prep(Prep p, float* __restrict__ ws){
  int a = blockIdx.y;
  int i = blockIdx.x * blockDim.x + threadIdx.x;
  if (i < p.n[a]) ws[p.o[a] + i] = p.s[a][i];
}

// ---------------- K1: bidirectional 15-step GRU; grid 512 (dir = bid>>8) ----
// 512 thr = 8 grps x 8 l.  8 waves/block = exactly 2 waves/EU (1 block/CU,
// LDS 139 KB), so amdgpu_waves_per_eu(2,2) raises the VGPR budget to the HW
// max of 256/wave -- room for the compiler's hoisted weight-load pipeline
// (the 128-cap was forcing 0.8 GB of scratch spill traffic, R7-R9).
__global__ __launch_bounds__(512)
__attribute__((amdgpu_waves_per_eu(2, 2)))
void k_gru(const float* __restrict__ obs, float* __restrict__ ws){
  __shared__ float smem[35584];          // 139 KB
  float* s_u  = smem;                    // 192*64 = 12288   u[g][node]
  float* s_cb = smem + 12288;            // 64*196 = 12544   cb[node][grp*24 + half*12 + g*4 + il]
  float* s_h0 = smem + 24832;            // 64*68  = 4352    obs -> h_enc -> state (even write)
  float* s_h1 = smem + 29184;            // 64*68  = 4352    state (odd write)
  float* s_ap = smem + 33536;            // 2048             logit partials, 2 buffers
  const int tid = threadIdx.x;
  const int nl  = tid & 63;
  const int grp = __builtin_amdgcn_readfirstlane(tid >> 6);
  const int dir = blockIdx.x >> 8;
  const int base = (blockIdx.x & 255) * 64;

  // P0: stage obs tile [node][68] into s_h0
  for (int k = tid; k < 4096; k += 512)
    s_h0[(k>>6)*68 + (k&63)] = obs[base*64 + k];
  __syncthreads();

  // P1: h_enc for own 8 l's
  const float* wenc = ws + OFF_WENC;
  const float* benc = ws + OFF_BENC;
  {
    float he[8];
    #pragma unroll
    for (int il = 0; il < 8; il++) he[il] = benc[grp*8 + il];
    #pragma unroll
    for (int dq = 0; dq < 16; dq++){
      float4 o4 = *(const float4*)&s_h0[nl*68 + 4*dq];
      #pragma unroll
      for (int il = 0; il < 8; il++){
        int l = grp*8 + il;
        he[il] += o4.x*wenc[(4*dq+0)*64+l] + o4.y*wenc[(4*dq+1)*64+l]
                + o4.z*wenc[(4*dq+2)*64+l] + o4.w*wenc[(4*dq+3)*64+l];
      }
    }
    __syncthreads();
    #pragma unroll
    for (int il = 0; il < 8; il++) s_h0[nl*68 + grp*8 + il] = fmaxf(he[il], 0.0f);
  }
  __syncthreads();

  const float* wih = ws + (dir ? OFF_WIHB : OFF_WIHF);
  const float* bih = ws + (dir ? OFF_BIHB : OFF_BIHF);
  const float* bhh = ws + (dir ? OFF_BHHB : OFF_BHHF);

  // P2a: u[g][node] -> s_u, two half-passes of 12 accumulators
  #pragma unroll
  for (int half = 0; half < 2; half++){
    float ua[12];
    #pragma unroll
    for (int c = 0; c < 12; c++) ua[c] = 0.f;
    #pragma unroll
    for (int dq = 0; dq < 16; dq++){
      float4 h4 = *(const float4*)&s_h0[nl*68 + 4*dq];
      #pragma unroll
      for (int c = 0; c < 12; c++){
        int row = (c>>2)*64 + grp*8 + half*4 + (c&3);
        const float* wr = wih + row*128 + 64 + 4*dq;
        ua[c] += h4.x*wr[0] + h4.y*wr[1] + h4.z*wr[2] + h4.w*wr[3];
      }
    }
    #pragma unroll
    for (int c = 0; c < 12; c++)
      s_u[((c>>2)*64 + grp*8 + half*4 + (c&3))*64 + nl] = ua[c];
  }

  // P2b: cb -> s_cb, two half-passes.  Layout per grp: half*12 + g*4 + il.
  // g<2 (r,z): bih+bhh folded.  g==2 (n): bih_n + Wih_n.h_i ONLY.
  float bhn[8];
  #pragma unroll
  for (int q = 0; q < 8; q++) bhn[q] = bhh[128 + grp*8 + q];
  #pragma unroll
  for (int half = 0; half < 2; half++){
    float cbl[12];
    #pragma unroll
    for (int c = 0; c < 12; c++){
      int g = c>>2, l = grp*8 + half*4 + (c&3);
      cbl[c] = bih[g*64 + l] + (g < 2 ? bhh[g*64 + l] : 0.0f);
    }
    #pragma unroll
    for (int dq = 0; dq < 16; dq++){
      float4 h4 = *(const float4*)&s_h0[nl*68 + 4*dq];
      #pragma unroll
      for (int c = 0; c < 12; c++){
        int row = (c>>2)*64 + grp*8 + half*4 + (c&3);
        const float* wr = wih + row*128 + 4*dq;
        cbl[c] += h4.x*wr[0] + h4.y*wr[1] + h4.z*wr[2] + h4.w*wr[3];
      }
    }
    #pragma unroll
    for (int m = 0; m < 3; m++)
      *(float4*)&s_cb[nl*196 + grp*24 + half*12 + 4*m] =
        make_float4(cbl[4*m], cbl[4*m+1], cbl[4*m+2], cbl[4*m+3]);
  }
  __syncthreads();                        // all P2 reads/writes done

  // P3: 15-step recurrence.  Step 0 skips Whh.h (h=0).
  const float* whh   = ws + (dir ? OFF_WHHB : OFF_WHHF);
  const float* whard = ws + OFF_WHARD + dir*128;    // rows l (fwd) / 64+l (bwd)
  float* yout        = ws + (dir ? OFF_YB : OFF_YF);
  const int i_b   = nl & 15;
  const int jbase = nl & 48;

  float hv[8];
  #pragma unroll
  for (int q = 0; q < 8; q++) hv[q] = 0.0f;

  for (int kk = 0; kk < 15; kk++){
    const int t  = dir ? (14 - kk) : kk;
    const int jl = jbase | (t + (t >= i_b ? 1 : 0));
    float* shr = (kk & 1) ? s_h1 : s_h0;      // read (kk=0: skipped, h=0)
    float* shw = (kk & 1) ? s_h0 : s_h1;      // write
    float* sap = s_ap + (kk & 1)*1024;

    float pa0 = 0.f, pa1 = 0.f;
    #pragma unroll
    for (int half = 0; half < 2; half++){
      // acc: r/z init from cb; n-gate accumulates PURE Whh_n.h (starts 0)
      float acc[12];
      #pragma unroll
      for (int m = 0; m < 2; m++){
        float4 c4 = *(const float4*)&s_cb[nl*196 + grp*24 + half*12 + 4*m];
        acc[4*m]=c4.x; acc[4*m+1]=c4.y; acc[4*m+2]=c4.z; acc[4*m+3]=c4.w;
      }
      #pragma unroll
      for (int c = 8; c < 12; c++) acc[c] = 0.f;

      if (kk > 0){
        #pragma unroll
        for (int dq = 0; dq < 16; dq++){
          float4 h4 = *(const float4*)&shr[nl*68 + 4*dq];
          #pragma unroll
          for (int c = 0; c < 12; c++){
            int row = (c>>2)*64 + grp*8 + half*4 + (c&3);
            const float* wr = whh + row*64 + 4*dq;
            acc[c] += h4.x*wr[0] + h4.y*wr[1] + h4.z*wr[2] + h4.w*wr[3];
          }
        }
      }

      #pragma unroll
      for (int il = 0; il < 4; il++){
        int l = grp*8 + half*4 + il;
        float cbn = s_cb[nl*196 + grp*24 + half*12 + 8 + il];
        float r = sigf(acc[il]     + s_u[(l      )*64 + jl]);
        float z = sigf(acc[4 + il] + s_u[(64 + l )*64 + jl]);
        float n = tanhfast(cbn + s_u[(128+l)*64 + jl]
                           + r*(bhn[half*4 + il] + acc[8 + il]));
        float hnew = (1.0f - z)*n + z*hv[half*4 + il];
        hv[half*4 + il] = hnew;
        pa0 += hnew * whard[l*2 + 0];
        pa1 += hnew * whard[l*2 + 1];
      }
    }
    *(float4*)&shw[nl*68 + grp*8    ] = make_float4(hv[0],hv[1],hv[2],hv[3]);
    *(float4*)&shw[nl*68 + grp*8 + 4] = make_float4(hv[4],hv[5],hv[6],hv[7]);
    sap[      grp*64 + nl] = pa0;
    sap[512 + grp*64 + nl] = pa1;
    __syncthreads();
    if (tid < 64){
      float a0 = 0.f, a1 = 0.f;
      #pragma unroll
      for (int g = 0; g < 8; g++){ a0 += sap[g*64 + nl]; a1 += sap[512 + g*64 + nl]; }
      *(float2*)&yout[((base + nl)*15 + t)*2] = make_float2(a0, a1);
    }
  }
}

// ---------------- K2: qkv + gumbel + attention + final GRU cell -------------
// 256 thr = 4 grps x 16; 2 blocks/CU (64 KB LDS) = 2 waves/EU -> same
// waves_per_eu(2,2) treatment for a 256-VGPR budget.
__global__ __launch_bounds__(256)
__attribute__((amdgpu_waves_per_eu(2, 2)))
void k_attn(const float* __restrict__ obs,
            const float* __restrict__ hid,
            const float* __restrict__ gum,
            float* __restrict__ ws,
            float* __restrict__ out){
  __shared__ float smem[16384];          // 64 KB
  float* s_k  = smem;                    // 4096  [a][node]
  float* s_v  = smem + 4096;             // 4096
  float* s_x  = smem + 8192;             // 4352  [node][68]: obs -> h_enc -> x
  float* s_sp = smem + 12544;            // 3840  score partials
  float* s_h0 = smem;                    // 4352, aliases dead s_k/s_v (late phases)
  const int tid = threadIdx.x;
  const int nl  = tid & 63;
  const int grp = __builtin_amdgcn_readfirstlane(tid >> 6);
  const int base = blockIdx.x * 64;
  const int node = base + nl;

  // P0: stage obs
  for (int k = tid; k < 4096; k += 256)
    s_x[(k>>6)*68 + (k&63)] = obs[base*64 + k];
  __syncthreads();

  // P1: h_enc own 16 l's
  const float* wenc = ws + OFF_WENC; const float* benc = ws + OFF_BENC;
  {
    float he[16];
    #pragma unroll
    for (int il = 0; il < 16; il++) he[il] = benc[grp*16 + il];
    #pragma unroll
    for (int dq = 0; dq < 16; dq++){
      float4 o4 = *(const float4*)&s_x[nl*68 + 4*dq];
      #pragma unroll
      for (int il = 0; il < 16; il++){
        int l = grp*16 + il;
        he[il] += o4.x*wenc[(4*dq+0)*64+l] + o4.y*wenc[(4*dq+1)*64+l]
                + o4.z*wenc[(4*dq+2)*64+l] + o4.w*wenc[(4*dq+3)*64+l];
      }
    }
    __syncthreads();
    #pragma unroll
    for (int il = 0; il < 16; il++) s_x[nl*68 + grp*16 + il] = fmaxf(he[il], 0.0f);
  }
  __syncthreads();

  // P2: k, v, q in three sequential passes
  const float* wq = ws+OFF_WQ; const float* wk = ws+OFF_WK;
  const float* wv = ws+OFF_WV; const float* bv = ws+OFF_BV;
  {
    float ak[16];
    #pragma unroll
    for (int il = 0; il < 16; il++) ak[il] = 0.f;
    #pragma unroll
    for (int dq = 0; dq < 16; dq++){
      float4 h4 = *(const float4*)&s_x[nl*68 + 4*dq];
      #pragma unroll
      for (int il = 0; il < 16; il++){
        int a = grp*16 + il;
        ak[il] += h4.x*wk[(4*dq+0)*64+a] + h4.y*wk[(4*dq+1)*64+a]
                + h4.z*wk[(4*dq+2)*64+a] + h4.w*wk[(4*dq+3)*64+a];
      }
    }
    #pragma unroll
    for (int il = 0; il < 16; il++) s_k[(grp*16+il)*64 + nl] = ak[il];
  }
  {
    float av[16];
    #pragma unroll
    for (int il = 0; il < 16; il++) av[il] = bv[grp*16+il];
    #pragma unroll
    for (int dq = 0; dq < 16; dq++){
      float4 h4 = *(const float4*)&s_x[nl*68 + 4*dq];
      #pragma unroll
      for (int il = 0; il < 16; il++){
        int a = grp*16 + il;
        av[il] += h4.x*wv[(4*dq+0)*64+a] + h4.y*wv[(4*dq+1)*64+a]
                + h4.z*wv[(4*dq+2)*64+a] + h4.w*wv[(4*dq+3)*64+a];
      }
    }
    #pragma unroll
    for (int il = 0; il < 16; il++) s_v[(grp*16+il)*64 + nl] = fmaxf(av[il], 0.f);
  }
  float aq[16];
  #pragma unroll
  for (int il = 0; il < 16; il++) aq[il] = 0.f;
  #pragma unroll
  for (int dq = 0; dq < 16; dq++){
    float4 h4 = *(const float4*)&s_x[nl*68 + 4*dq];
    #pragma unroll
    for (int il = 0; il < 16; il++){
      int a = grp*16 + il;
      aq[il] += h4.x*wq[(4*dq+0)*64+a] + h4.y*wq[(4*dq+1)*64+a]
              + h4.z*wq[(4*dq+2)*64+a] + h4.w*wq[(4*dq+3)*64+a];
    }
  }
  __syncthreads();

  // P3: scores (partial over this grp's 16 a-dims)
  const int i_b = nl & 15, jbase = nl & 48;
  #pragma unroll
  for (int t = 0; t < 15; t++){
    int jl = jbase | (t + (t >= i_b ? 1 : 0));
    float s = 0.f;
    #pragma unroll
    for (int il = 0; il < 16; il++) s += aq[il]*s_k[(grp*16+il)*64 + jl];
    s_sp[t*256 + grp*64 + nl] = s;
  }
  __syncthreads();

  // P4: softmax + gumbel-hard coefficient
  float coeff[15];
  {
    float sc[15];
    float m = -1e30f;
    #pragma unroll
    for (int t = 0; t < 15; t++){
      float s = (s_sp[t*256+nl] + s_sp[t*256+64+nl] +
                 s_sp[t*256+128+nl] + s_sp[t*256+192+nl]) * 0.125f;
      sc[t] = s; m = fmaxf(m, s);
    }
    float den = 0.f;
    #pragma unroll
    for (int t = 0; t < 15; t++){ sc[t] = __expf(sc[t]-m); den += sc[t]; }
    float rden = 1.0f/den;
    const float bh0 = ws[OFF_BHARD], bh1 = ws[OFF_BHARD+1];
    const float* yF = ws + OFF_YF; const float* yB = ws + OFF_YB;
    #pragma unroll
    for (int t = 0; t < 15; t++){
      int rowb = (node*15 + t)*2;
      float y0 = yF[rowb]   + yB[rowb]   + bh0;
      float y1 = yF[rowb+1] + yB[rowb+1] + bh1;
      float2 u2 = *(const float2*)&gum[rowb];
      float g0 = -__logf(-__logf(u2.x + EPSG) + EPSG);
      float g1 = -__logf(-__logf(u2.y + EPSG) + EPSG);
      float w  = sigf(((y1+g1) - (y0+g0)) * (1.0f/TAU_));
      coeff[t] = sc[t]*rden*w;
    }
  }

  // P5: x accumulation into s_x (h values dead since P3 barrier)
  {
    float xa[16];
    #pragma unroll
    for (int il = 0; il < 16; il++) xa[il] = 0.f;
    #pragma unroll
    for (int t = 0; t < 15; t++){
      int jl = jbase | (t + (t >= i_b ? 1 : 0));
      float c = coeff[t];
      #pragma unroll
      for (int il = 0; il < 16; il++) xa[il] += c*s_v[(grp*16+il)*64 + jl];
    }
    __syncthreads();                      // all s_v reads done before alias write
    #pragma unroll
    for (int il = 0; il < 16; il++) s_x[nl*68 + grp*16 + il] = xa[il];
  }

  // P6: stage hidden_state into s_h0 (aliases dead s_k/s_v)
  for (int k = tid; k < 4096; k += 256)
    s_h0[(k>>6)*68 + (k&63)] = hid[base*64 + k];
  __syncthreads();

  // P7: final GRU cell, il-blocked by 4
  const float* wih = ws+OFF_WIHC; const float* whc = ws+OFF_WHHC;
  const float* bih = ws+OFF_BIHC; const float* bhc = ws+OFF_BHHC;
  for (int ilb = 0; ilb < 4; ilb++){
    float ac[24];
    #pragma unroll
    for (int q = 0; q < 4; q++){
      int l = grp*16 + ilb*4 + q;
      ac[q*6+0] = bih[l]; ac[q*6+1] = bih[64+l]; ac[q*6+2] = bih[128+l];
      ac[q*6+3] = bhc[l]; ac[q*6+4] = bhc[64+l]; ac[q*6+5] = bhc[128+l];
    }
    #pragma unroll
    for (int dq = 0; dq < 16; dq++){
      float4 x4 = *(const float4*)&s_x [nl*68 + 4*dq];
      float4 h4 = *(const float4*)&s_h0[nl*68 + 4*dq];
      #pragma unroll
      for (int q = 0; q < 4; q++){
        int l = grp*16 + ilb*4 + q;
        const float* w0 = wih + (l     )*64 + 4*dq;
        const float* w1 = wih + (64 + l)*64 + 4*dq;
        const float* w2 = wih + (128+ l)*64 + 4*dq;
        const float* m0 = whc + (l     )*64 + 4*dq;
        const float* m1 = whc + (64 + l)*64 + 4*dq;
        const float* m2 = whc + (128+ l)*64 + 4*dq;
        ac[q*6+0] += x4.x*w0[0]+x4.y*w0[1]+x4.z*w0[2]+x4.w*w0[3];
        ac[q*6+1] += x4.x*w1[0]+x4.y*w1[1]+x4.z*w1[2]+x4.w*w1[3];
        ac[q*6+2] += x4.x*w2[0]+x4.y*w2[1]+x4.z*w2[2]+x4.w*w2[3];
        ac[q*6+3] += h4.x*m0[0]+h4.y*m0[1]+h4.z*m0[2]+h4.w*m0[3];
        ac[q*6+4] += h4.x*m1[0]+h4.y*m1[1]+h4.z*m1[2]+h4.w*m1[3];
        ac[q*6+5] += h4.x*m2[0]+h4.y*m2[1]+h4.z*m2[2]+h4.w*m2[3];
      }
    }
    #pragma unroll
    for (int q = 0; q < 4; q++){
      int l = grp*16 + ilb*4 + q;
      float r = sigf(ac[q*6+0] + ac[q*6+3]);
      float z = sigf(ac[q*6+1] + ac[q*6+4]);
      float n = tanhfast(ac[q*6+2] + r*ac[q*6+5]);
      out[node*64 + l] = (1.0f - z)*n + z*s_h0[nl*68 + l];
    }
  }
}

extern "C" void kernel_launch(void* const* d_in, const int* in_sizes, int n_in,
                              void* d_out, int out_size, void* d_ws, size_t ws_size,
                              hipStream_t stream){
  if (ws_size < (size_t)WS_FLOATS * sizeof(float)) return;
  float* ws = (float*)d_ws;
  static const int offs[20] = {OFF_WENC, OFF_BENC, OFF_WIHF, OFF_WHHF, OFF_BIHF, OFF_BHHF,
      OFF_WIHB, OFF_WHHB, OFF_BIHB, OFF_BHHB, OFF_WHARD, OFF_BHARD, OFF_WQ, OFF_WK, OFF_WV,
      OFF_BV, OFF_WIHC, OFF_WHHC, OFF_BIHC, OFF_BHHC};
  Prep p;
  for (int i = 0; i < 20; i++){
    p.s[i] = (const float*)d_in[3 + i];
    p.n[i] = in_sizes[3 + i];
    p.o[i] = offs[i];
  }
  hipLaunchKernelGGL(k_prep, dim3(96, 20), dim3(256), 0, stream, p, ws);
  hipLaunchKernelGGL(k_gru,  dim3(512),    dim3(512), 0, stream,
                     (const float*)d_in[0], ws);
  hipLaunchKernelGGL(k_attn, dim3(256),    dim3(256), 0, stream,
                     (const float*)d_in[0], (const float*)d_in[1],
                     (const float*)d_in[2], ws, (float*)d_out);
}

// Round 11
// 388.452 us; speedup vs baseline: 3.2487x; 3.2487x over previous
//
#include <hip/hip_runtime.h>
#include <hip/hip_bf16.h>
#include <stdint.h>

// B=1024, N=16, D=64, H=64, A=64 -> 16384 nodes. All tensors fp32.
#define NNODE 16384
#define TAU_ 0.01f
#define EPSG 1e-10f

// ---- workspace layout (float offsets); total 1,114,112 floats = 4.25 MB ----
#define OFF_WENC 0
#define OFF_BENC 4096
#define OFF_WIHF 4160
#define OFF_WHHF 28736
#define OFF_BIHF 41024
#define OFF_BHHF 41216
#define OFF_WIHB 41408
#define OFF_WHHB 65984
#define OFF_BIHB 78272
#define OFF_BHHB 78464
#define OFF_WHARD 78656
#define OFF_BHARD 78912
#define OFF_WQ 78914
#define OFF_WK 83010
#define OFF_WV 87106
#define OFF_BV 91202
#define OFF_WIHC 91266
#define OFF_WHHC 103554
#define OFF_BIHC 115842
#define OFF_BHHC 116034
#define OFF_YF 131072
#define OFF_YB (OFF_YF + 491520)
#define WS_FLOATS (OFF_YB + 491520)

typedef float  v4f __attribute__((ext_vector_type(4)));
typedef short  v8s __attribute__((ext_vector_type(8)));

__device__ __forceinline__ float sigf(float x){ return 1.0f/(1.0f + __expf(-x)); }
__device__ __forceinline__ float tanhfast(float x){ return 1.0f - 2.0f/(__expf(2.0f*x)+1.0f); }
__device__ __forceinline__ unsigned short f2bf(float f){
  __hip_bfloat16 h = __float2bfloat16(f);
  return *reinterpret_cast<unsigned short*>(&h);
}
__device__ __forceinline__ float bf2f(unsigned short u){
  union { unsigned int i; float f; } v; v.i = ((unsigned int)u) << 16; return v.f;
}

// ---------------- K0: copy all weights into contiguous ws ----------------
struct Prep {
  const float* s[20];
  int n[20];
  int o[20];
};
__global__ void k_prep(Prep p, float* __restrict__ ws){
  int a = blockIdx.y;
  int i = blockIdx.x * blockDim.x + threadIdx.x;
  if (i < p.n[a]) ws[p.o[a] + i] = p.s[a][i];
}

// ---------------- K1: bidirectional 15-step GRU via bf16 MFMA ---------------
// grid 512 (dir = bid>>8).  512 thr = 8 waves; wave w: lw=w>>2 (l half),
// nw=w&3 (node-tile of 16).  Per step: G[192x64] = Whh x H as 12 MFMAs/wave
// (6 tiles x K=64 in 2 chunks).  Whh lives in 48 persistent VGPRs (A-frags,
// loaded once) -> zero per-step weight traffic.  cb in MFMA C regs.  H in
// bf16 LDS [node][l] stride 80 (16B-aligned b128 B-frags), double-buffered.
// W_hard logits by the tid<64 reducer from bf16 h.  LDS 69 KB -> 2 blk/CU.
__global__ __launch_bounds__(512, 1) void k_gru(const float* __restrict__ obs,
                                                float* __restrict__ ws){
  __shared__ float smem[17664];               // 69 KB
  float* s_u2 = smem;                         // [j-node][196] rows g*64+l : 12544
  float* s_h  = smem + 12544;                 // fp32 obs->h_enc [node][68] : 4352 (region 5120)
  unsigned short* s_hbu = (unsigned short*)(smem + 12544); // bf16 h, 2 x [64][80] ushorts (aliases s_h)

  const int tid = threadIdx.x;
  const int nl  = tid & 63;
  const int grp = __builtin_amdgcn_readfirstlane(tid >> 6);
  const int dir = blockIdx.x >> 8;
  const int base = (blockIdx.x & 255) * 64;
  const int lw = grp >> 2;                    // 0,1 : l-range 32*lw..+32
  const int nw = grp & 3;                     // node-tile
  const int q  = nl >> 4;                     // quad
  const int i_c = nl & 15;
  const int node = 16*nw + i_c;               // this thread's target node (local)

  // P0: stage obs tile [node][68]
  for (int k = tid; k < 4096; k += 512)
    s_h[(k>>6)*68 + (k&63)] = obs[base*64 + k];
  __syncthreads();

  // P1: h_enc (old mapping: 8 l's per thread)
  const float* wenc = ws + OFF_WENC;
  const float* benc = ws + OFF_BENC;
  {
    float he[8];
    #pragma unroll
    for (int il = 0; il < 8; il++) he[il] = benc[grp*8 + il];
    #pragma unroll
    for (int dq = 0; dq < 16; dq++){
      float4 o4 = *(const float4*)&s_h[nl*68 + 4*dq];
      #pragma unroll
      for (int il = 0; il < 8; il++){
        int l = grp*8 + il;
        he[il] += o4.x*wenc[(4*dq+0)*64+l] + o4.y*wenc[(4*dq+1)*64+l]
                + o4.z*wenc[(4*dq+2)*64+l] + o4.w*wenc[(4*dq+3)*64+l];
      }
    }
    __syncthreads();
    #pragma unroll
    for (int il = 0; il < 8; il++) s_h[nl*68 + grp*8 + il] = fmaxf(he[il], 0.0f);
  }
  __syncthreads();

  const float* wih = ws + (dir ? OFF_WIHB : OFF_WIHF);
  const float* bih = ws + (dir ? OFF_BIHB : OFF_BIHF);
  const float* bhh = ws + (dir ? OFF_BHHB : OFF_BHHF);
  const float* whh = ws + (dir ? OFF_WHHB : OFF_WHHF);

  // P2a: u[row][j-node] -> s_u2[j][196].  Thread: j = its node, rows = its
  // 8 l's x 3 gates (24 dots over h_enc[node]).
  {
    v4f ua[6];
    #pragma unroll
    for (int m = 0; m < 6; m++) ua[m] = (v4f){0.f,0.f,0.f,0.f};
    #pragma unroll
    for (int dq = 0; dq < 16; dq++){
      float4 h4 = *(const float4*)&s_h[node*68 + 4*dq];
      #pragma unroll
      for (int t2 = 0; t2 < 2; t2++){
        int l0 = 32*lw + 16*t2 + 4*q;
        #pragma unroll
        for (int g = 0; g < 3; g++){
          #pragma unroll
          for (int r = 0; r < 4; r++){
            const float* wr = wih + (g*64 + l0 + r)*128 + 64 + 4*dq;
            ua[t2*3+g][r] += h4.x*wr[0] + h4.y*wr[1] + h4.z*wr[2] + h4.w*wr[3];
          }
        }
      }
    }
    #pragma unroll
    for (int t2 = 0; t2 < 2; t2++){
      int l0 = 32*lw + 16*t2 + 4*q;
      #pragma unroll
      for (int g = 0; g < 3; g++)
        *(v4f*)&s_u2[node*196 + g*64 + l0] = ua[t2*3+g];
    }
  }

  // P2b: cb -> persistent C-layout registers.  cbr/cbz fold bhh; cbn = bih_n
  // + WihL_n.h_i only (bhh_n/Whh_n stay inside r).
  v4f cbr[2], cbz[2], cbn[2], bhn4[2];
  #pragma unroll
  for (int t2 = 0; t2 < 2; t2++){
    int l0 = 32*lw + 16*t2 + 4*q;
    float4 b0 = *(const float4*)&bih[l0];
    float4 h0 = *(const float4*)&bhh[l0];
    float4 b1 = *(const float4*)&bih[64+l0];
    float4 h1 = *(const float4*)&bhh[64+l0];
    float4 b2 = *(const float4*)&bih[128+l0];
    float4 n2 = *(const float4*)&bhh[128+l0];
    cbr[t2] = (v4f){b0.x+h0.x, b0.y+h0.y, b0.z+h0.z, b0.w+h0.w};
    cbz[t2] = (v4f){b1.x+h1.x, b1.y+h1.y, b1.z+h1.z, b1.w+h1.w};
    cbn[t2] = (v4f){b2.x, b2.y, b2.z, b2.w};
    bhn4[t2] = (v4f){n2.x, n2.y, n2.z, n2.w};
  }
  #pragma unroll
  for (int dq = 0; dq < 16; dq++){
    float4 h4 = *(const float4*)&s_h[node*68 + 4*dq];
    #pragma unroll
    for (int t2 = 0; t2 < 2; t2++){
      int l0 = 32*lw + 16*t2 + 4*q;
      #pragma unroll
      for (int r = 0; r < 4; r++){
        const float* w0 = wih + (l0 + r)*128 + 4*dq;
        const float* w1 = wih + (64 + l0 + r)*128 + 4*dq;
        const float* w2 = wih + (128 + l0 + r)*128 + 4*dq;
        cbr[t2][r] += h4.x*w0[0] + h4.y*w0[1] + h4.z*w0[2] + h4.w*w0[3];
        cbz[t2][r] += h4.x*w1[0] + h4.y*w1[1] + h4.z*w1[2] + h4.w*w1[3];
        cbn[t2][r] += h4.x*w2[0] + h4.y*w2[1] + h4.z*w2[2] + h4.w*w2[3];
      }
    }
  }

  // P2c: Whh -> bf16 A-fragments (persistent).  A[m=lane&15][k=quad*8+j];
  // tile rows: g*64 + 32*lw + 16*t2 + m; K chunk kc*32.
  v8s afr[2][2], afz[2][2], afn[2][2];
  #pragma unroll
  for (int t2 = 0; t2 < 2; t2++){
    #pragma unroll
    for (int kc = 0; kc < 2; kc++){
      #pragma unroll
      for (int g = 0; g < 3; g++){
        int row = g*64 + 32*lw + 16*t2 + i_c;
        const float* wp = whh + row*64 + kc*32 + q*8;
        float4 w0 = *(const float4*)wp;
        float4 w1 = *(const float4*)(wp+4);
        union { v8s v; unsigned short u[8]; } P;
        P.u[0]=f2bf(w0.x); P.u[1]=f2bf(w0.y); P.u[2]=f2bf(w0.z); P.u[3]=f2bf(w0.w);
        P.u[4]=f2bf(w1.x); P.u[5]=f2bf(w1.y); P.u[6]=f2bf(w1.z); P.u[7]=f2bf(w1.w);
        if (g==0) afr[t2][kc]=P.v; else if (g==1) afz[t2][kc]=P.v; else afn[t2][kc]=P.v;
      }
    }
  }
  __syncthreads();   // all s_h reads done; s_hbu (alias) may now be written

  // P3: 15-step recurrence
  const float* whard = ws + OFF_WHARD + dir*128;
  float* yout        = ws + (dir ? OFF_YB : OFF_YF);

  float hv[8];
  #pragma unroll
  for (int m = 0; m < 8; m++) hv[m] = 0.0f;

  for (int kk = 0; kk < 15; kk++){
    const int t  = dir ? (14 - kk) : kk;
    const int j  = t + (t >= i_c ? 1 : 0);
    const int jl = 16*nw + j;
    const int rb = kk & 1;            // read buffer (valid for kk>0)
    const int wb = (kk + 1) & 1;      // write buffer

    v8s b0, b1;
    if (kk > 0){
      const unsigned short* rp = s_hbu + rb*5120 + node*80 + q*8;
      b0 = *(const v8s*)(rp);
      b1 = *(const v8s*)(rp + 32);
    }

    #pragma unroll
    for (int t2 = 0; t2 < 2; t2++){
      int l0 = 32*lw + 16*t2 + 4*q;
      v4f dr = cbr[t2], dz = cbz[t2];
      v4f dn = (v4f){0.f,0.f,0.f,0.f};
      if (kk > 0){
        dr = __builtin_amdgcn_mfma_f32_16x16x32_bf16(afr[t2][0], b0, dr, 0,0,0);
        dr = __builtin_amdgcn_mfma_f32_16x16x32_bf16(afr[t2][1], b1, dr, 0,0,0);
        dz = __builtin_amdgcn_mfma_f32_16x16x32_bf16(afz[t2][0], b0, dz, 0,0,0);
        dz = __builtin_amdgcn_mfma_f32_16x16x32_bf16(afz[t2][1], b1, dz, 0,0,0);
        dn = __builtin_amdgcn_mfma_f32_16x16x32_bf16(afn[t2][0], b0, dn, 0,0,0);
        dn = __builtin_amdgcn_mfma_f32_16x16x32_bf16(afn[t2][1], b1, dn, 0,0,0);
      }
      v4f ur = *(const v4f*)&s_u2[jl*196 +       l0];
      v4f uz = *(const v4f*)&s_u2[jl*196 +  64 + l0];
      v4f un = *(const v4f*)&s_u2[jl*196 + 128 + l0];
      float hn[4];
      #pragma unroll
      for (int r = 0; r < 4; r++){
        float rg = sigf(dr[r] + ur[r]);
        float zg = sigf(dz[r] + uz[r]);
        float ng = tanhfast(cbn[t2][r] + un[r] + rg*(bhn4[t2][r] + dn[r]));
        float hnew = (1.0f - zg)*ng + zg*hv[t2*4+r];
        hv[t2*4+r] = hnew;
        hn[r] = hnew;
      }
      unsigned int p0 = (unsigned int)f2bf(hn[0]) | ((unsigned int)f2bf(hn[1]) << 16);
      unsigned int p1 = (unsigned int)f2bf(hn[2]) | ((unsigned int)f2bf(hn[3]) << 16);
      *(uint2*)(s_hbu + wb*5120 + node*80 + l0) = make_uint2(p0, p1);
    }
    __syncthreads();

    // reducer: y[node][t] = h_new . W_hard rows (fwd: l, bwd: 64+l)
    if (tid < 64){
      const unsigned short* hb = s_hbu + wb*5120 + tid*80;
      float a0 = 0.f, a1 = 0.f;
      #pragma unroll
      for (int c = 0; c < 16; c++){
        uint2 hw = *(const uint2*)(hb + c*4);
        float f0 = bf2f((unsigned short)(hw.x & 0xffff));
        float f1 = bf2f((unsigned short)(hw.x >> 16));
        float f2 = bf2f((unsigned short)(hw.y & 0xffff));
        float f3 = bf2f((unsigned short)(hw.y >> 16));
        int l = c*4;
        a0 += f0*whard[(l  )*2] + f1*whard[(l+1)*2] + f2*whard[(l+2)*2] + f3*whard[(l+3)*2];
        a1 += f0*whard[(l  )*2+1] + f1*whard[(l+1)*2+1] + f2*whard[(l+2)*2+1] + f3*whard[(l+3)*2+1];
      }
      *(float2*)&yout[((base + tid)*15 + t)*2] = make_float2(a0, a1);
    }
  }
}

// ---------------- K2: qkv + gumbel + attention + final GRU cell -------------
// 256 thr = 4 grps x 16. Sequential low-live passes (R9-verified form).
__global__ __launch_bounds__(256, 1) void k_attn(const float* __restrict__ obs,
                                                 const float* __restrict__ hid,
                                                 const float* __restrict__ gum,
                                                 float* __restrict__ ws,
                                                 float* __restrict__ out){
  __shared__ float smem[16384];          // 64 KB
  float* s_k  = smem;                    // 4096  [a][node]
  float* s_v  = smem + 4096;             // 4096
  float* s_x  = smem + 8192;             // 4352  [node][68]: obs -> h_enc -> x
  float* s_sp = smem + 12544;            // 3840  score partials
  float* s_h0 = smem;                    // 4352, aliases dead s_k/s_v (late phases)
  const int tid = threadIdx.x;
  const int nl  = tid & 63;
  const int grp = __builtin_amdgcn_readfirstlane(tid >> 6);
  const int base = blockIdx.x * 64;
  const int node = base + nl;

  for (int k = tid; k < 4096; k += 256)
    s_x[(k>>6)*68 + (k&63)] = obs[base*64 + k];
  __syncthreads();

  const float* wenc = ws + OFF_WENC; const float* benc = ws + OFF_BENC;
  {
    float he[16];
    #pragma unroll
    for (int il = 0; il < 16; il++) he[il] = benc[grp*16 + il];
    #pragma unroll
    for (int dq = 0; dq < 16; dq++){
      float4 o4 = *(const float4*)&s_x[nl*68 + 4*dq];
      #pragma unroll
      for (int il = 0; il < 16; il++){
        int l = grp*16 + il;
        he[il] += o4.x*wenc[(4*dq+0)*64+l] + o4.y*wenc[(4*dq+1)*64+l]
                + o4.z*wenc[(4*dq+2)*64+l] + o4.w*wenc[(4*dq+3)*64+l];
      }
    }
    __syncthreads();
    #pragma unroll
    for (int il = 0; il < 16; il++) s_x[nl*68 + grp*16 + il] = fmaxf(he[il], 0.0f);
  }
  __syncthreads();

  const float* wq = ws+OFF_WQ; const float* wk = ws+OFF_WK;
  const float* wv = ws+OFF_WV; const float* bv = ws+OFF_BV;
  {
    float ak[16];
    #pragma unroll
    for (int il = 0; il < 16; il++) ak[il] = 0.f;
    #pragma unroll
    for (int dq = 0; dq < 16; dq++){
      float4 h4 = *(const float4*)&s_x[nl*68 + 4*dq];
      #pragma unroll
      for (int il = 0; il < 16; il++){
        int a = grp*16 + il;
        ak[il] += h4.x*wk[(4*dq+0)*64+a] + h4.y*wk[(4*dq+1)*64+a]
                + h4.z*wk[(4*dq+2)*64+a] + h4.w*wk[(4*dq+3)*64+a];
      }
    }
    #pragma unroll
    for (int il = 0; il < 16; il++) s_k[(grp*16+il)*64 + nl] = ak[il];
  }
  {
    float av[16];
    #pragma unroll
    for (int il = 0; il < 16; il++) av[il] = bv[grp*16+il];
    #pragma unroll
    for (int dq = 0; dq < 16; dq++){
      float4 h4 = *(const float4*)&s_x[nl*68 + 4*dq];
      #pragma unroll
      for (int il = 0; il < 16; il++){
        int a = grp*16 + il;
        av[il] += h4.x*wv[(4*dq+0)*64+a] + h4.y*wv[(4*dq+1)*64+a]
                + h4.z*wv[(4*dq+2)*64+a] + h4.w*wv[(4*dq+3)*64+a];
      }
    }
    #pragma unroll
    for (int il = 0; il < 16; il++) s_v[(grp*16+il)*64 + nl] = fmaxf(av[il], 0.f);
  }
  float aq[16];
  #pragma unroll
  for (int il = 0; il < 16; il++) aq[il] = 0.f;
  #pragma unroll
  for (int dq = 0; dq < 16; dq++){
    float4 h4 = *(const float4*)&s_x[nl*68 + 4*dq];
    #pragma unroll
    for (int il = 0; il < 16; il++){
      int a = grp*16 + il;
      aq[il] += h4.x*wq[(4*dq+0)*64+a] + h4.y*wq[(4*dq+1)*64+a]
              + h4.z*wq[(4*dq+2)*64+a] + h4.w*wq[(4*dq+3)*64+a];
    }
  }
  __syncthreads();

  const int i_b = nl & 15, jbase = nl & 48;
  #pragma unroll
  for (int t = 0; t < 15; t++){
    int jl = jbase | (t + (t >= i_b ? 1 : 0));
    float s = 0.f;
    #pragma unroll
    for (int il = 0; il < 16; il++) s += aq[il]*s_k[(grp*16+il)*64 + jl];
    s_sp[t*256 + grp*64 + nl] = s;
  }
  __syncthreads();

  float coeff[15];
  {
    float sc[15];
    float m = -1e30f;
    #pragma unroll
    for (int t = 0; t < 15; t++){
      float s = (s_sp[t*256+nl] + s_sp[t*256+64+nl] +
                 s_sp[t*256+128+nl] + s_sp[t*256+192+nl]) * 0.125f;
      sc[t] = s; m = fmaxf(m, s);
    }
    float den = 0.f;
    #pragma unroll
    for (int t = 0; t < 15; t++){ sc[t] = __expf(sc[t]-m); den += sc[t]; }
    float rden = 1.0f/den;
    const float bh0 = ws[OFF_BHARD], bh1 = ws[OFF_BHARD+1];
    const float* yF = ws + OFF_YF; const float* yB = ws + OFF_YB;
    #pragma unroll
    for (int t = 0; t < 15; t++){
      int rowb = (node*15 + t)*2;
      float y0 = yF[rowb]   + yB[rowb]   + bh0;
      float y1 = yF[rowb+1] + yB[rowb+1] + bh1;
      float2 u2 = *(const float2*)&gum[rowb];
      float g0 = -__logf(-__logf(u2.x + EPSG) + EPSG);
      float g1 = -__logf(-__logf(u2.y + EPSG) + EPSG);
      float w  = sigf(((y1+g1) - (y0+g0)) * (1.0f/TAU_));
      coeff[t] = sc[t]*rden*w;
    }
  }

  {
    float xa[16];
    #pragma unroll
    for (int il = 0; il < 16; il++) xa[il] = 0.f;
    #pragma unroll
    for (int t = 0; t < 15; t++){
      int jl = jbase | (t + (t >= i_b ? 1 : 0));
      float c = coeff[t];
      #pragma unroll
      for (int il = 0; il < 16; il++) xa[il] += c*s_v[(grp*16+il)*64 + jl];
    }
    __syncthreads();
    #pragma unroll
    for (int il = 0; il < 16; il++) s_x[nl*68 + grp*16 + il] = xa[il];
  }

  for (int k = tid; k < 4096; k += 256)
    s_h0[(k>>6)*68 + (k&63)] = hid[base*64 + k];
  __syncthreads();

  const float* wih = ws+OFF_WIHC; const float* whc = ws+OFF_WHHC;
  const float* bih = ws+OFF_BIHC; const float* bhc = ws+OFF_BHHC;
  for (int ilb = 0; ilb < 4; ilb++){
    float ac[24];
    #pragma unroll
    for (int p = 0; p < 4; p++){
      int l = grp*16 + ilb*4 + p;
      ac[p*6+0] = bih[l]; ac[p*6+1] = bih[64+l]; ac[p*6+2] = bih[128+l];
      ac[p*6+3] = bhc[l]; ac[p*6+4] = bhc[64+l]; ac[p*6+5] = bhc[128+l];
    }
    #pragma unroll
    for (int dq = 0; dq < 16; dq++){
      float4 x4 = *(const float4*)&s_x [nl*68 + 4*dq];
      float4 h4 = *(const float4*)&s_h0[nl*68 + 4*dq];
      #pragma unroll
      for (int p = 0; p < 4; p++){
        int l = grp*16 + ilb*4 + p;
        const float* w0 = wih + (l     )*64 + 4*dq;
        const float* w1 = wih + (64 + l)*64 + 4*dq;
        const float* w2 = wih + (128+ l)*64 + 4*dq;
        const float* m0 = whc + (l     )*64 + 4*dq;
        const float* m1 = whc + (64 + l)*64 + 4*dq;
        const float* m2 = whc + (128+ l)*64 + 4*dq;
        ac[p*6+0] += x4.x*w0[0]+x4.y*w0[1]+x4.z*w0[2]+x4.w*w0[3];
        ac[p*6+1] += x4.x*w1[0]+x4.y*w1[1]+x4.z*w1[2]+x4.w*w1[3];
        ac[p*6+2] += x4.x*w2[0]+x4.y*w2[1]+x4.z*w2[2]+x4.w*w2[3];
        ac[p*6+3] += h4.x*m0[0]+h4.y*m0[1]+h4.z*m0[2]+h4.w*m0[3];
        ac[p*6+4] += h4.x*m1[0]+h4.y*m1[1]+h4.z*m1[2]+h4.w*m1[3];
        ac[p*6+5] += h4.x*m2[0]+h4.y*m2[1]+h4.z*m2[2]+h4.w*m2[3];
      }
    }
    #pragma unroll
    for (int p = 0; p < 4; p++){
      int l = grp*16 + ilb*4 + p;
      float r = sigf(ac[p*6+0] + ac[p*6+3]);
      float z = sigf(ac[p*6+1] + ac[p*6+4]);
      float n = tanhfast(ac[p*6+2] + r*ac[p*6+5]);
      out[node*64 + l] = (1.0f - z)*n + z*s_h0[nl*68 + l];
    }
  }
}

extern "C" void kernel_launch(void* const* d_in, const int* in_sizes, int n_in,
                              void* d_out, int out_size, void* d_ws, size_t ws_size,
                              hipStream_t stream){
  if (ws_size < (size_t)WS_FLOATS * sizeof(float)) return;
  float* ws = (float*)d_ws;
  static const int offs[20] = {OFF_WENC, OFF_BENC, OFF_WIHF, OFF_WHHF, OFF_BIHF, OFF_BHHF,
      OFF_WIHB, OFF_WHHB, OFF_BIHB, OFF_BHHB, OFF_WHARD, OFF_BHARD, OFF_WQ, OFF_WK, OFF_WV,
      OFF_BV, OFF_WIHC, OFF_WHHC, OFF_BIHC, OFF_BHHC};
  Prep p;
  for (int i = 0; i < 20; i++){
    p.s[i] = (const float*)d_in[3 + i];
    p.n[i] = in_sizes[3 + i];
    p.o[i] = offs[i];
  }
  hipLaunchKernelGGL(k_prep, dim3(96, 20), dim3(256), 0, stream, p, ws);
  hipLaunchKernelGGL(k_gru,  dim3(512),    dim3(512), 0, stream,
                     (const float*)d_in[0], ws);
  hipLaunchKernelGGL(k_attn, dim3(256),    dim3(256), 0, stream,
                     (const float*)d_in[0], (const float*)d_in[1],
                     (const float*)d_in[2], ws, (float*)d_out);
}